// Round 14
// baseline (115.430 us; speedup 1.0000x reference)
//
#include <hip/hip_runtime.h>

#define T_STEPS 20
#define BATCH   65536
#define HIDN    64
#define GATES   256
#define HSTR    72       // hl row stride (bf16); 144B keeps b128 alignment, breaks pow2

typedef __bf16 bf16x8 __attribute__((ext_vector_type(8)));
typedef float  f32x4  __attribute__((ext_vector_type(4)));
typedef float  f32x2  __attribute__((ext_vector_type(2)));
typedef unsigned int uint32;
typedef uint32 uint32x4 __attribute__((ext_vector_type(4)));

#define L2E 1.4426950408889634f

#if __has_builtin(__builtin_amdgcn_exp2f)
#define EXP2F(x) __builtin_amdgcn_exp2f(x)
#else
#define EXP2F(x) exp2f(x)
#endif
#if __has_builtin(__builtin_amdgcn_rcpf)
#define RCPF(x) __builtin_amdgcn_rcpf(x)
#else
#define RCPF(x) (1.0f / (x))
#endif

__device__ __forceinline__ uint32 pack2bf16(float a, float b) {
    unsigned short ua = __builtin_bit_cast(unsigned short, (__bf16)a);
    unsigned short ub = __builtin_bit_cast(unsigned short, (__bf16)b);
    return (uint32)ua | ((uint32)ub << 16);
}

// R11 kernel EXACTLY (best: 108.7us — 2 m-blocks/wave, bias+x in one MFMA,
// log2e folded, 7-trans activation, 60 VGPR no-spill), residency experiment:
//  - CHUNKS=1, grid 2048 WGs = 8 WGs/CU offered to the dispatcher.
//  - plain __launch_bounds__(256,4): codegen budget 128 VGPR (same codegen
//    path that produced 56-60 VGPR in R8/R9); crucially NO waves_per_eu
//    max-clamp, so the RUNTIME may co-schedule 8 WGs/CU at 60 VGPR (fits
//    the 8-waves/SIMD tier at <=64 VGPR; LDS 12.3KB x 8 = 98KB < 160KB).
// R5/R7/R10 lesson: never request the 8-wave tier at CODEGEN time (the
// allocator clamps below real pressure and spills GBs); offering it at
// runtime via grid size is safe (R6 datapoint: +5%).
__global__ __launch_bounds__(256, 4)
void Encoder_6949257085628_kernel(const float* __restrict__ obs,
                                  const float* __restrict__ W_emb,
                                  const float* __restrict__ b_emb,
                                  const float* __restrict__ W_ih,
                                  const float* __restrict__ W_hh,
                                  const float* __restrict__ b_ih,
                                  const float* __restrict__ b_hh,
                                  float* __restrict__ out) {
    __shared__ float wcbc[GATES * 3];                    // 3 KB (scaled Wc,bc)
    __shared__ __align__(16) __bf16 hlb[2][32 * HSTR];   // 2 x 4.5 KB, dbuf

    const int tid  = threadIdx.x;
    const int jtw  = tid >> 6;       // wave index = hidden-quarter
    const int lane = tid & 63;
    const int q    = lane >> 4;      // 0..3 (K-group)
    const int c16  = lane & 15;
    const bool qz  = (q == 0);

    // ---- fold embedding into gate map with log2e scaling ----
    {
        int g = tid;  // exactly 256 threads
        float sf = ((g >> 6) == 2) ? (2.0f * L2E) : (-L2E);
        float a0 = 0.f, a1 = 0.f, ab = 0.f;
        for (int e = 0; e < 64; ++e) {
            float wie = W_ih[g * 64 + e];
            a0 = fmaf(wie, W_emb[e * 2 + 0], a0);
            a1 = fmaf(wie, W_emb[e * 2 + 1], a1);
            ab = fmaf(wie, b_emb[e], ab);
        }
        wcbc[g * 3 + 0] = a0 * sf;
        wcbc[g * 3 + 1] = a1 * sf;
        wcbc[g * 3 + 2] = (ab + b_ih[g] + b_hh[g]) * sf;
    }

    // ---- this wave's 8 W_hh B-fragments, scaled, in registers ----
    bf16x8 bfr[4][2];
    #pragma unroll
    for (int f = 0; f < 4; ++f) {
        const float sf = (f == 2) ? (2.0f * L2E) : (-L2E);
        const int rowW = f * 64 + jtw * 16 + c16;
        #pragma unroll
        for (int ks = 0; ks < 2; ++ks) {
            const float* p = W_hh + rowW * 64 + ks * 32 + q * 8;
            f32x4 lo = *(const f32x4*)p;
            f32x4 hi = *(const f32x4*)(p + 4);
            bf16x8 b;
            b[0] = (__bf16)(lo[0] * sf); b[1] = (__bf16)(lo[1] * sf);
            b[2] = (__bf16)(lo[2] * sf); b[3] = (__bf16)(lo[3] * sf);
            b[4] = (__bf16)(hi[0] * sf); b[5] = (__bf16)(hi[1] * sf);
            b[6] = (__bf16)(hi[2] * sf); b[7] = (__bf16)(hi[3] * sf);
            bfr[f][ks] = b;
        }
    }
    __syncthreads();   // wcbc staged

    // ---- x/bias B-frag words (per f): [w0,w1 | bc_hi,bc_lo | 0..], q==0 ----
    uint32 bxw0[4], bxw1[4];
    #pragma unroll
    for (int f = 0; f < 4; ++f) {
        int col = f * 64 + jtw * 16 + c16;
        float w0s = wcbc[col * 3 + 0];
        float w1s = wcbc[col * 3 + 1];
        float bcs = wcbc[col * 3 + 2];
        float blo = bcs - (float)((__bf16)bcs);
        bxw0[f] = qz ? pack2bf16(w0s, w1s) : 0u;
        bxw1[f] = qz ? pack2bf16(bcs, blo) : 0u;
    }
    const uint32 axw1 = qz ? 0x3F803F80u : 0u;   // [1.0,1.0] bf16, K-slots 2,3

    const int rbw  = blockIdx.x * 32;            // this WG's 32 batch rows
    const int hOff = jtw * 16 + c16;             // this lane's hidden index

    float cst[2][4];
    #pragma unroll
    for (int m = 0; m < 2; ++m)
        #pragma unroll
        for (int r = 0; r < 4; ++r) cst[m][r] = 0.f;

    // lane tracks x of row (m*16 + c16); only q==0 lanes feed the MFMA
    f32x2 xc[2];
    #pragma unroll
    for (int m = 0; m < 2; ++m)
        xc[m] = *(const f32x2*)&obs[(size_t)(rbw + m * 16 + c16) * 2];

    auto ax_of = [&](f32x2 xv) -> bf16x8 {
        uint32 w0 = qz ? pack2bf16(xv[0], xv[1]) : 0u;
        return __builtin_bit_cast(bf16x8, uint32x4{w0, axw1, 0u, 0u});
    };
    auto bx_of = [&](int f) -> bf16x8 {
        return __builtin_bit_cast(bf16x8, uint32x4{bxw0[f], bxw1[f], 0u, 0u});
    };
    // 7-trans activation: 5 exp2 + 2 rcp per hidden cell
    auto act_store = [&](f32x4 (&acc)[4], int m, __bf16* hw, bool last) {
        #pragma unroll
        for (int r = 0; r < 4; ++r) {
            float A = EXP2F(acc[0][r]);            // e^{-x_i}
            float E = EXP2F(acc[1][r]);            // e^{-x_f}
            float B = EXP2F(acc[2][r]);            // e^{2 x_g}
            float C = EXP2F(acc[3][r]);            // e^{-x_o}
            float pA = 1.0f + A, pB = 1.0f + B, pE = 1.0f + E;
            float P  = pA * pB;                    // (1+A)(1+B)
            float Bm = B - 1.0f;
            // c = [cst*P + (B-1)(1+E)] / [(1+E)*P]
            float num = fmaf(cst[m][r], P, Bm * pE);
            float cc  = num * RCPF(pE * P);
            cst[m][r] = cc;
            float D  = EXP2F(cc * (2.0f * L2E));   // e^{2c}
            // h = o * tanh(c) = (D-1) / [(1+C)(1+D)]
            float h  = (D - 1.0f) * RCPF((1.0f + C) * (1.0f + D));
            if (!last) {
                hw[(m * 16 + q * 4 + r) * HSTR + hOff] = (__bf16)h;
            } else {
                out[(size_t)(rbw + m * 16 + q * 4 + r) * HIDN + hOff] = h;
            }
        }
    };

    bf16x8 a0c[2], a1c[2];   // h A-frags, read right after each barrier

    // ---- t = 0 (no h): gates = x/bias MFMA only ----
    {
        f32x4 acc[2][4];
        #pragma unroll
        for (int m = 0; m < 2; ++m) {
            bf16x8 ax = ax_of(xc[m]);
            #pragma unroll
            for (int f = 0; f < 4; ++f)
                acc[m][f] = __builtin_amdgcn_mfma_f32_16x16x32_bf16(
                    ax, bx_of(f), f32x4{0.f, 0.f, 0.f, 0.f}, 0, 0, 0);
        }
        #pragma unroll
        for (int m = 0; m < 2; ++m)
            xc[m] = *(const f32x2*)&obs[(size_t)(BATCH * 2) + (size_t)(rbw + m * 16 + c16) * 2];
        act_store(acc[0], 0, hlb[0], false);
        act_store(acc[1], 1, hlb[0], false);
        __syncthreads();
        #pragma unroll
        for (int m = 0; m < 2; ++m) {
            a0c[m] = *(const bf16x8*)&hlb[0][(m * 16 + c16) * HSTR + q * 8];
            a1c[m] = *(const bf16x8*)&hlb[0][(m * 16 + c16) * HSTR + 32 + q * 8];
        }
    }

    // ---- t = 1..18, branch-free ----
    #pragma unroll 1
    for (int t = 1; t < T_STEPS - 1; ++t) {
        f32x4 acc[2][4];
        #pragma unroll
        for (int m = 0; m < 2; ++m) {
            bf16x8 ax = ax_of(xc[m]);
            #pragma unroll
            for (int f = 0; f < 4; ++f) {
                acc[m][f] = __builtin_amdgcn_mfma_f32_16x16x32_bf16(
                    ax, bx_of(f), f32x4{0.f, 0.f, 0.f, 0.f}, 0, 0, 0);
                acc[m][f] = __builtin_amdgcn_mfma_f32_16x16x32_bf16(
                    a0c[m], bfr[f][0], acc[m][f], 0, 0, 0);
                acc[m][f] = __builtin_amdgcn_mfma_f32_16x16x32_bf16(
                    a1c[m], bfr[f][1], acc[m][f], 0, 0, 0);
            }
        }
        #pragma unroll
        for (int m = 0; m < 2; ++m)
            xc[m] = *(const f32x2*)&obs[(size_t)(t + 1) * (BATCH * 2) + (size_t)(rbw + m * 16 + c16) * 2];
        act_store(acc[0], 0, hlb[t & 1], false);
        act_store(acc[1], 1, hlb[t & 1], false);
        __syncthreads();
        #pragma unroll
        for (int m = 0; m < 2; ++m) {
            a0c[m] = *(const bf16x8*)&hlb[t & 1][(m * 16 + c16) * HSTR + q * 8];
            a1c[m] = *(const bf16x8*)&hlb[t & 1][(m * 16 + c16) * HSTR + 32 + q * 8];
        }
    }

    // ---- t = 19: write fp32 output ----
    {
        f32x4 acc[2][4];
        #pragma unroll
        for (int m = 0; m < 2; ++m) {
            bf16x8 ax = ax_of(xc[m]);
            #pragma unroll
            for (int f = 0; f < 4; ++f) {
                acc[m][f] = __builtin_amdgcn_mfma_f32_16x16x32_bf16(
                    ax, bx_of(f), f32x4{0.f, 0.f, 0.f, 0.f}, 0, 0, 0);
                acc[m][f] = __builtin_amdgcn_mfma_f32_16x16x32_bf16(
                    a0c[m], bfr[f][0], acc[m][f], 0, 0, 0);
                acc[m][f] = __builtin_amdgcn_mfma_f32_16x16x32_bf16(
                    a1c[m], bfr[f][1], acc[m][f], 0, 0, 0);
            }
        }
        act_store(acc[0], 0, nullptr, true);
        act_store(acc[1], 1, nullptr, true);
    }
}

extern "C" void kernel_launch(void* const* d_in, const int* in_sizes, int n_in,
                              void* d_out, int out_size, void* d_ws, size_t ws_size,
                              hipStream_t stream) {
    const float* obs   = (const float*)d_in[0];
    const float* W_emb = (const float*)d_in[1];
    const float* b_emb = (const float*)d_in[2];
    const float* W_ih  = (const float*)d_in[3];
    const float* W_hh  = (const float*)d_in[4];
    const float* b_ih  = (const float*)d_in[5];
    const float* b_hh  = (const float*)d_in[6];
    float* out = (float*)d_out;

    dim3 grid(BATCH / 32);   // 2048 WGs: 8 WGs/CU offered at runtime
    dim3 block(256);
    Encoder_6949257085628_kernel<<<grid, block, 0, stream>>>(
        obs, W_emb, b_emb, W_ih, W_hh, b_ih, b_hh, out);
}

// Round 15
// 103.749 us; speedup vs baseline: 1.1126x; 1.1126x over previous
//
#include <hip/hip_runtime.h>

#define T_STEPS 20
#define BATCH   65536
#define HIDN    64
#define GATES   256
#define CHUNKS  2        // two 32-row chunks per WG -> 1024 WGs = 4/CU resident
#define HSTR    72       // hl row stride (bf16); 144B keeps b128 alignment, breaks pow2

typedef __bf16 bf16x8 __attribute__((ext_vector_type(8)));
typedef float  f32x4  __attribute__((ext_vector_type(4)));
typedef float  f32x2  __attribute__((ext_vector_type(2)));
typedef unsigned int uint32;
typedef uint32 uint32x4 __attribute__((ext_vector_type(4)));

#define L2E 1.4426950408889634f

#if __has_builtin(__builtin_amdgcn_exp2f)
#define EXP2F(x) __builtin_amdgcn_exp2f(x)
#else
#define EXP2F(x) exp2f(x)
#endif
#if __has_builtin(__builtin_amdgcn_rcpf)
#define RCPF(x) __builtin_amdgcn_rcpf(x)
#else
#define RCPF(x) (1.0f / (x))
#endif

__device__ __forceinline__ uint32 pack2bf16(float a, float b) {
    unsigned short ua = __builtin_bit_cast(unsigned short, (__bf16)a);
    unsigned short ub = __builtin_bit_cast(unsigned short, (__bf16)b);
    return (uint32)ua | ((uint32)ub << 16);
}

// R11 base EXACTLY (best: 108.7us — 2 m-blocks/wave, bias+x in one MFMA,
// log2e folded, 7-trans activation, waves_per_eu(4,4) -> 60 VGPR no-spill,
// 1024 WGs x 2 chunks). R15 single variable: PACKED-F32 activation math.
// The cell update's elementwise ops (adds/muls/fmas) are rewritten on
// row-PAIRS as f32x2 vectors so the backend can form VOP3P v_pk_add_f32 /
// v_pk_mul_f32 / v_pk_fma_f32 (CDNA4 full-rate, 2 f32 lanes per inst).
// exp2/rcp have no packed form and stay scalar. Expected: ~60 fewer VALU
// insts per wave-step (~5-8%). Numerics identical (pk ops are full fp32).
__global__ __launch_bounds__(256)
__attribute__((amdgpu_waves_per_eu(4, 4)))
void Encoder_6949257085628_kernel(const float* __restrict__ obs,
                                  const float* __restrict__ W_emb,
                                  const float* __restrict__ b_emb,
                                  const float* __restrict__ W_ih,
                                  const float* __restrict__ W_hh,
                                  const float* __restrict__ b_ih,
                                  const float* __restrict__ b_hh,
                                  float* __restrict__ out) {
    __shared__ float wcbc[GATES * 3];                    // 3 KB (scaled Wc,bc)
    __shared__ __align__(16) __bf16 hlb[2][32 * HSTR];   // 2 x 4.5 KB, dbuf

    const int tid  = threadIdx.x;
    const int jtw  = tid >> 6;       // wave index = hidden-quarter
    const int lane = tid & 63;
    const int q    = lane >> 4;      // 0..3 (K-group)
    const int c16  = lane & 15;
    const bool qz  = (q == 0);

    // ---- fold embedding into gate map with log2e scaling ----
    {
        int g = tid;  // exactly 256 threads
        float sf = ((g >> 6) == 2) ? (2.0f * L2E) : (-L2E);
        float a0 = 0.f, a1 = 0.f, ab = 0.f;
        for (int e = 0; e < 64; ++e) {
            float wie = W_ih[g * 64 + e];
            a0 = fmaf(wie, W_emb[e * 2 + 0], a0);
            a1 = fmaf(wie, W_emb[e * 2 + 1], a1);
            ab = fmaf(wie, b_emb[e], ab);
        }
        wcbc[g * 3 + 0] = a0 * sf;
        wcbc[g * 3 + 1] = a1 * sf;
        wcbc[g * 3 + 2] = (ab + b_ih[g] + b_hh[g]) * sf;
    }

    // ---- this wave's 8 W_hh B-fragments, scaled, in registers ----
    bf16x8 bfr[4][2];
    #pragma unroll
    for (int f = 0; f < 4; ++f) {
        const float sf = (f == 2) ? (2.0f * L2E) : (-L2E);
        const int rowW = f * 64 + jtw * 16 + c16;
        #pragma unroll
        for (int ks = 0; ks < 2; ++ks) {
            const float* p = W_hh + rowW * 64 + ks * 32 + q * 8;
            f32x4 lo = *(const f32x4*)p;
            f32x4 hi = *(const f32x4*)(p + 4);
            bf16x8 b;
            b[0] = (__bf16)(lo[0] * sf); b[1] = (__bf16)(lo[1] * sf);
            b[2] = (__bf16)(lo[2] * sf); b[3] = (__bf16)(lo[3] * sf);
            b[4] = (__bf16)(hi[0] * sf); b[5] = (__bf16)(hi[1] * sf);
            b[6] = (__bf16)(hi[2] * sf); b[7] = (__bf16)(hi[3] * sf);
            bfr[f][ks] = b;
        }
    }
    __syncthreads();   // wcbc staged

    // ---- x/bias B-frag words (per f): [w0,w1 | bc_hi,bc_lo | 0..], q==0 ----
    uint32 bxw0[4], bxw1[4];
    #pragma unroll
    for (int f = 0; f < 4; ++f) {
        int col = f * 64 + jtw * 16 + c16;
        float w0s = wcbc[col * 3 + 0];
        float w1s = wcbc[col * 3 + 1];
        float bcs = wcbc[col * 3 + 2];
        float blo = bcs - (float)((__bf16)bcs);
        bxw0[f] = qz ? pack2bf16(w0s, w1s) : 0u;
        bxw1[f] = qz ? pack2bf16(bcs, blo) : 0u;
    }
    const uint32 axw1 = qz ? 0x3F803F80u : 0u;   // [1.0,1.0] bf16, K-slots 2,3

    const int wgBase = blockIdx.x * (32 * CHUNKS);
    const int hOff   = jtw * 16 + c16;           // this lane's hidden index

    #pragma unroll 1
    for (int c = 0; c < CHUNKS; ++c) {
        const int rbw = wgBase + c * 32;
        __syncthreads();   // protects hlb reuse across chunks

        // c-state as row-pairs: cst[m][rp] covers rows {2rp, 2rp+1}
        f32x2 cst[2][2];
        #pragma unroll
        for (int m = 0; m < 2; ++m)
            #pragma unroll
            for (int rp = 0; rp < 2; ++rp) cst[m][rp] = f32x2{0.f, 0.f};

        // lane tracks x of row (m*16 + c16); only q==0 lanes feed the MFMA
        f32x2 xc[2];
        #pragma unroll
        for (int m = 0; m < 2; ++m)
            xc[m] = *(const f32x2*)&obs[(size_t)(rbw + m * 16 + c16) * 2];

        auto ax_of = [&](f32x2 xv) -> bf16x8 {
            uint32 w0 = qz ? pack2bf16(xv[0], xv[1]) : 0u;
            return __builtin_bit_cast(bf16x8, uint32x4{w0, axw1, 0u, 0u});
        };
        auto bx_of = [&](int f) -> bf16x8 {
            return __builtin_bit_cast(bf16x8, uint32x4{bxw0[f], bxw1[f], 0u, 0u});
        };
        // 7-trans activation on row-pairs; elementwise math as f32x2 so the
        // backend can form v_pk_{add,mul,fma}_f32.
        auto act_store = [&](f32x4 (&acc)[4], int m, __bf16* hw, bool last) {
            #pragma unroll
            for (int rp = 0; rp < 2; ++rp) {
                const int r0 = 2 * rp, r1 = 2 * rp + 1;
                f32x2 A{EXP2F(acc[0][r0]), EXP2F(acc[0][r1])};   // e^{-x_i}
                f32x2 E{EXP2F(acc[1][r0]), EXP2F(acc[1][r1])};   // e^{-x_f}
                f32x2 B{EXP2F(acc[2][r0]), EXP2F(acc[2][r1])};   // e^{2 x_g}
                f32x2 C{EXP2F(acc[3][r0]), EXP2F(acc[3][r1])};   // e^{-x_o}
                f32x2 one{1.0f, 1.0f};
                f32x2 pA = A + one, pB = B + one, pE = E + one;
                f32x2 P  = pA * pB;
                f32x2 Bm = B - one;
                f32x2 num = __builtin_elementwise_fma(cst[m][rp], P, Bm * pE);
                f32x2 den = pE * P;
                f32x2 rd{RCPF(den[0]), RCPF(den[1])};
                f32x2 cc = num * rd;
                cst[m][rp] = cc;
                f32x2 ccs = cc * f32x2{2.0f * L2E, 2.0f * L2E};
                f32x2 D{EXP2F(ccs[0]), EXP2F(ccs[1])};           // e^{2c}
                f32x2 hn = D - one;
                f32x2 hd = (one + C) * (one + D);
                f32x2 rh{RCPF(hd[0]), RCPF(hd[1])};
                f32x2 h  = hn * rh;
                if (!last) {
                    hw[(m * 16 + q * 4 + r0) * HSTR + hOff] = (__bf16)h[0];
                    hw[(m * 16 + q * 4 + r1) * HSTR + hOff] = (__bf16)h[1];
                } else {
                    out[(size_t)(rbw + m * 16 + q * 4 + r0) * HIDN + hOff] = h[0];
                    out[(size_t)(rbw + m * 16 + q * 4 + r1) * HIDN + hOff] = h[1];
                }
            }
        };

        bf16x8 a0c[2], a1c[2];   // h A-frags, read right after each barrier

        // ---- t = 0 (no h): gates = x/bias MFMA only ----
        {
            f32x4 acc[2][4];
            #pragma unroll
            for (int m = 0; m < 2; ++m) {
                bf16x8 ax = ax_of(xc[m]);
                #pragma unroll
                for (int f = 0; f < 4; ++f)
                    acc[m][f] = __builtin_amdgcn_mfma_f32_16x16x32_bf16(
                        ax, bx_of(f), f32x4{0.f, 0.f, 0.f, 0.f}, 0, 0, 0);
            }
            #pragma unroll
            for (int m = 0; m < 2; ++m)
                xc[m] = *(const f32x2*)&obs[(size_t)(BATCH * 2) + (size_t)(rbw + m * 16 + c16) * 2];
            act_store(acc[0], 0, hlb[0], false);
            act_store(acc[1], 1, hlb[0], false);
            __syncthreads();
            #pragma unroll
            for (int m = 0; m < 2; ++m) {
                a0c[m] = *(const bf16x8*)&hlb[0][(m * 16 + c16) * HSTR + q * 8];
                a1c[m] = *(const bf16x8*)&hlb[0][(m * 16 + c16) * HSTR + 32 + q * 8];
            }
        }

        // ---- t = 1..18, branch-free ----
        #pragma unroll 1
        for (int t = 1; t < T_STEPS - 1; ++t) {
            f32x4 acc[2][4];
            #pragma unroll
            for (int m = 0; m < 2; ++m) {
                bf16x8 ax = ax_of(xc[m]);
                #pragma unroll
                for (int f = 0; f < 4; ++f) {
                    acc[m][f] = __builtin_amdgcn_mfma_f32_16x16x32_bf16(
                        ax, bx_of(f), f32x4{0.f, 0.f, 0.f, 0.f}, 0, 0, 0);
                    acc[m][f] = __builtin_amdgcn_mfma_f32_16x16x32_bf16(
                        a0c[m], bfr[f][0], acc[m][f], 0, 0, 0);
                    acc[m][f] = __builtin_amdgcn_mfma_f32_16x16x32_bf16(
                        a1c[m], bfr[f][1], acc[m][f], 0, 0, 0);
                }
            }
            #pragma unroll
            for (int m = 0; m < 2; ++m)
                xc[m] = *(const f32x2*)&obs[(size_t)(t + 1) * (BATCH * 2) + (size_t)(rbw + m * 16 + c16) * 2];
            act_store(acc[0], 0, hlb[t & 1], false);
            act_store(acc[1], 1, hlb[t & 1], false);
            __syncthreads();
            #pragma unroll
            for (int m = 0; m < 2; ++m) {
                a0c[m] = *(const bf16x8*)&hlb[t & 1][(m * 16 + c16) * HSTR + q * 8];
                a1c[m] = *(const bf16x8*)&hlb[t & 1][(m * 16 + c16) * HSTR + 32 + q * 8];
            }
        }

        // ---- t = 19: write fp32 output ----
        {
            f32x4 acc[2][4];
            #pragma unroll
            for (int m = 0; m < 2; ++m) {
                bf16x8 ax = ax_of(xc[m]);
                #pragma unroll
                for (int f = 0; f < 4; ++f) {
                    acc[m][f] = __builtin_amdgcn_mfma_f32_16x16x32_bf16(
                        ax, bx_of(f), f32x4{0.f, 0.f, 0.f, 0.f}, 0, 0, 0);
                    acc[m][f] = __builtin_amdgcn_mfma_f32_16x16x32_bf16(
                        a0c[m], bfr[f][0], acc[m][f], 0, 0, 0);
                    acc[m][f] = __builtin_amdgcn_mfma_f32_16x16x32_bf16(
                        a1c[m], bfr[f][1], acc[m][f], 0, 0, 0);
                }
            }
            act_store(acc[0], 0, nullptr, true);
            act_store(acc[1], 1, nullptr, true);
        }
    }
}

extern "C" void kernel_launch(void* const* d_in, const int* in_sizes, int n_in,
                              void* d_out, int out_size, void* d_ws, size_t ws_size,
                              hipStream_t stream) {
    const float* obs   = (const float*)d_in[0];
    const float* W_emb = (const float*)d_in[1];
    const float* b_emb = (const float*)d_in[2];
    const float* W_ih  = (const float*)d_in[3];
    const float* W_hh  = (const float*)d_in[4];
    const float* b_ih  = (const float*)d_in[5];
    const float* b_hh  = (const float*)d_in[6];
    float* out = (float*)d_out;

    dim3 grid(BATCH / (32 * CHUNKS));  // 1024 WGs = 4 per CU, all resident
    dim3 block(256);
    Encoder_6949257085628_kernel<<<grid, block, 0, stream>>>(
        obs, W_emb, b_emb, W_ih, W_hh, b_ih, b_hh, out);
}